// Round 15
// baseline (109.148 us; speedup 1.0000x reference)
//
#include <hip/hip_runtime.h>
#include <hip/hip_bf16.h>

#define NELEM 16384
#define DIN 768
#define DMID 128
#define DOUT 4

typedef __attribute__((ext_vector_type(8))) short short8;
typedef __attribute__((ext_vector_type(4))) float f32x4;

__device__ __forceinline__ unsigned f2bf(float f) {
    unsigned u = __float_as_uint(f);
    return (u + 0x7FFFu + ((u >> 16) & 1u)) >> 16;   // RNE bf16
}
__device__ __forceinline__ unsigned wscan_inc(unsigned x, int lane) {
    unsigned inc = x;
#pragma unroll
    for (int off = 1; off < 64; off <<= 1) {
        unsigned y = __shfl_up(inc, off);
        if (lane >= off) inc += y;
    }
    return inc;
}
__device__ __forceinline__ unsigned popc4(uint4 x) {
    return (unsigned)(__popc(x.x) + __popc(x.y) + __popc(x.z) + __popc(x.w));
}

// ===========================================================================
// FAST5 ws layout (identical to R14):
//   Gb@0(64K) SD@65536(64K) WtG@131072(192K) stage@327680(128K u64)
//   LCnt@458752(128) RBT@458880(512K)  -> 983,168 B
// MEASUREMENT ROUND: rank_kernel launched x3 (idempotent) to decompose
// the ~55us sort-side cost:  T = prep + 3*rank + fused = 70.1 + 2*rank.
// ===========================================================================
#define FAST5_WS 983168

// K1: prep. 32 blocks (one per batch row) x 256 threads. LDS atomics only.
__global__ __launch_bounds__(256) void prep_kernel(
    const int* __restrict__ vocab_ids, const float* __restrict__ W1,
    unsigned* __restrict__ Gb, unsigned short* __restrict__ WtG,
    unsigned* __restrict__ RBT, unsigned long long* __restrict__ stage,
    unsigned* __restrict__ LCnt) {
    __shared__ unsigned lbm[4096];       // 16 KB row vocab bitmap (2^17 bits)
    __shared__ unsigned voc[512];
    __shared__ unsigned short gel[512];
    __shared__ unsigned gcnt[512];
    __shared__ unsigned gstart[512];
    __shared__ unsigned part[256];
    __shared__ unsigned wsumL[4];

    const int t = threadIdx.x;
    const int b = blockIdx.x;
    const int lane = t & 63;
    const int wv = t >> 6;

    // ---- W1^T -> bf16 (coalesced reads) ----
#pragma unroll
    for (int i = 0; i < 12; ++i) {
        int j = b * 3072 + i * 256 + t;   // 0..98303
        int k = j >> 7, c = j & 127;
        WtG[c * DIN + k] = (unsigned short)f2bf(W1[j]);
    }

    // ---- load row + zero LDS ----
#pragma unroll
    for (int i = 0; i < 16; ++i) lbm[t + 256 * i] = 0;
    gcnt[t] = 0; gcnt[t + 256] = 0;
#pragma unroll
    for (int q = 0; q < 2; ++q) {
        int s = q * 256 + t;
        voc[s] = (unsigned)vocab_ids[b * 512 + s];
    }
    __syncthreads();
    // ---- local bitmap mark (LDS atomics only) ----
#pragma unroll
    for (int q = 0; q < 2; ++q) {
        unsigned v = voc[q * 256 + t];
        atomicOr(&lbm[v >> 5], 1u << (v & 31u));
    }
    __syncthreads();
    // ---- dump row bitmap to global, transposed: RBT[w*32+b] ----
#pragma unroll
    for (int i = 0; i < 16; ++i) {
        int w = i * 256 + t;
        RBT[w * 32 + b] = lbm[w];
    }
    // ---- local chunk-scan (16 words/thread) -> part[]; LCnt = #groups ----
    {
        unsigned sum = 0;
#pragma unroll
        for (int j = 0; j < 16; ++j) sum += (unsigned)__popc(lbm[t * 16 + j]);
        unsigned inc = wscan_inc(sum, lane);
        if (lane == 63) wsumL[wv] = inc;
        __syncthreads();
        unsigned woff = 0;
        for (int i = 0; i < wv; ++i) woff += wsumL[i];
        part[t] = woff + inc - sum;
        if (t == 255) LCnt[b] = woff + inc;
        __syncthreads();
    }
    // ---- per-element group index g; count group sizes ----
#pragma unroll
    for (int q = 0; q < 2; ++q) {
        int s = q * 256 + t;
        unsigned v = voc[s];
        unsigned lw = v >> 5, c = lw >> 4;
        unsigned g = part[c];
        for (unsigned j = c * 16; j < lw; ++j) g += (unsigned)__popc(lbm[j]);
        g += (unsigned)__popc(lbm[lw] & ((1u << (v & 31u)) - 1u));
        gel[s] = (unsigned short)g;
        atomicAdd(&gcnt[g], 1u);                      // LDS, counts only
    }
    __syncthreads();
    // ---- exclusive scan gcnt[512] -> gstart ----
    {
        unsigned a = gcnt[2 * t], b2 = gcnt[2 * t + 1];
        unsigned pair = a + b2;
        unsigned inc = wscan_inc(pair, lane);
        if (lane == 63) wsumL[wv] = inc;
        __syncthreads();
        unsigned woff = 0;
        for (int i = 0; i < wv; ++i) woff += wsumL[i];
        unsigned excl = woff + inc - pair;
        gstart[2 * t] = excl;
        gstart[2 * t + 1] = excl + a;
    }
    __syncthreads();
    // ---- member index + grouped Gb write + leader staging ----
#pragma unroll
    for (int q = 0; q < 2; ++q) {
        int s = q * 256 + t;
        unsigned g = gel[s];
        unsigned v = voc[s];
        unsigned m = 0;
        if (gcnt[g] > 1) {                            // rare
            for (int j = 0; j < s; ++j) if (voc[j] == v) ++m;
        }
        Gb[b * 512 + gstart[g] + m] = (v << 9) | (unsigned)s;
        if (m == 0) {
            unsigned sdval = ((unsigned)b << 19) | (gstart[g] << 10) | gcnt[g];
            stage[b * 512 + g] = ((unsigned long long)v << 32) | sdval;
        }
    }
}

// K2: rank. 32 blocks x 256 threads (idempotent; launched x3 this round).
__global__ __launch_bounds__(256) void rank_kernel(
    const unsigned* __restrict__ RBT,
    const unsigned long long* __restrict__ stage,
    const unsigned* __restrict__ LCnt,
    unsigned* __restrict__ SD, float* __restrict__ out_ids) {
    __shared__ unsigned pre1[4096];      // 16 KB: global bit-prefix per word
    __shared__ unsigned wsumL[4];
    __shared__ unsigned Ush;

    const int t = threadIdx.x;
    const int b = blockIdx.x;
    const int lane = t & 63;
    const int wv = t >> 6;
    const uint4* rb4 = (const uint4*)RBT;

    // ---- stream scan: thread t owns words w in [t*16, t*16+16) ----
    {
        unsigned loc[16];
        unsigned run = 0;
#pragma unroll
        for (int i = 0; i < 16; ++i) {
            loc[i] = run;
            const uint4* p = rb4 + (t * 16 + i) * 8;   // 32 row-words = 8 uint4
            unsigned s = 0;
#pragma unroll
            for (int q = 0; q < 8; ++q) s += popc4(p[q]);
            run += s;
        }
        unsigned inc = wscan_inc(run, lane);
        if (lane == 63) wsumL[wv] = inc;
        __syncthreads();
        unsigned woff = 0;
        for (int i = 0; i < wv; ++i) woff += wsumL[i];
        unsigned excl = woff + inc - run;
#pragma unroll
        for (int i = 0; i < 16; ++i) pre1[t * 16 + i] = excl + loc[i];
        if (t == 255) Ush = woff + inc;
        __syncthreads();
    }
    const unsigned U = Ush;

    // ---- leaders of row b: rank + SD + ids ----
    const unsigned cnt = LCnt[b];
    for (unsigned l = t; l < cnt; l += 256) {
        unsigned long long sv = stage[b * 512 + l];
        unsigned v = (unsigned)(sv >> 32);
        unsigned sdval = (unsigned)sv;
        unsigned w = v >> 5, bit = v & 31u;
        unsigned maskLT = (1u << bit) - 1u;
        unsigned rank = pre1[w];
        const unsigned* col = RBT + w * 32;
#pragma unroll
        for (int bb = 0; bb < 32; ++bb) {
            unsigned word = col[bb];
            rank += (unsigned)__popc(word & maskLT);
            if (bb < b) rank += (word >> bit) & 1u;
        }
        SD[rank] = sdval;
        out_ids[2 * rank + 0] = (float)v;
        out_ids[2 * rank + 1] = (float)b;
    }
    // ---- pad slots >= U ----
    for (int u = (int)U + b * 256 + t; u < NELEM; u += 32 * 256) {
        SD[u] = 0u;
        out_ids[2 * u + 0] = 0.0f;
        out_ids[2 * u + 1] = 0.0f;
    }
}

// ===========================================================================
// K3: MFMA fused kernel (proven R10-R14). 1024 blocks x 256 thr, 16 rows.
// ===========================================================================
#define FBM 16
__global__ __launch_bounds__(256) void fused_kernel(
    const unsigned* __restrict__ Gb,
    const unsigned* __restrict__ SD,
    const unsigned short* __restrict__ WtG,
    const float* __restrict__ emb,
    const float* __restrict__ b1,
    const float* __restrict__ enc,
    float* __restrict__ out_enc) {
    __shared__ char smem[20736];

    const int t = threadIdx.x;
    const int u0 = blockIdx.x * FBM;
    const int l = t & 63;
    const int w = t >> 6;

    const int ar = t >> 4;
    const int ak4 = t & 15;
    const unsigned sdw = SD[u0 + ar];
    const int lenA = (int)(sdw & 1023u);
    const unsigned embBase = (sdw >> 19) << 9;
    const unsigned gb0 = embBase + ((sdw >> 10) & 511u);

    f32x4 acc0 = {0.f, 0.f, 0.f, 0.f};
    f32x4 acc1 = {0.f, 0.f, 0.f, 0.f};

    for (int kk = 0; kk < DIN; kk += 64) {
        __syncthreads();
        {
            float s0 = 0.f, s1 = 0.f, s2 = 0.f, s3 = 0.f;
            const float* base = emb + (size_t)(kk + ak4 * 4);
            for (int p = 0; p < lenA; ++p) {
                unsigned idx = embBase + (Gb[gb0 + p] & 511u);
                const float4 e4 = *(const float4*)(base + (size_t)idx * DIN);
                s0 += e4.x; s1 += e4.y; s2 += e4.z; s3 += e4.w;
            }
            uint2 packed;
            packed.x = f2bf(s0) | (f2bf(s1) << 16);
            packed.y = f2bf(s2) | (f2bf(s3) << 16);
            *(uint2*)(smem + ar * 144 + ak4 * 8) = packed;
        }
        {
#pragma unroll
            for (int i = 0; i < 4; ++i) {
                int q = t + i * 256;
                int c = q >> 3;
                int uo = q & 7;
                uint4 dv = *(const uint4*)(WtG + (size_t)c * DIN + kk + uo * 8);
                *(uint4*)(smem + 2304 + c * 144 + uo * 16) = dv;
            }
        }
        __syncthreads();
        {
            const int arow = l & 15;
            const int ull = l >> 4;
#pragma unroll
            for (int kf = 0; kf < 2; ++kf) {
                short8 aF = *(const short8*)(smem + arow * 144 + kf * 64 + ull * 16);
                short8 bF0 = *(const short8*)(smem + 2304 + (w * 32 + arow) * 144 + kf * 64 + ull * 16);
                short8 bF1 = *(const short8*)(smem + 2304 + (w * 32 + 16 + arow) * 144 + kf * 64 + ull * 16);
                acc0 = __builtin_amdgcn_mfma_f32_16x16x32_bf16(aF, bF0, acc0, 0, 0, 0);
                acc1 = __builtin_amdgcn_mfma_f32_16x16x32_bf16(aF, bF1, acc1, 0, 0, 0);
            }
        }
    }
    __syncthreads();
    {
        float* Hs = (float*)smem;
        const int col0 = w * 32 + (l & 15);
        const int rbase = (l >> 4) * 4;
#pragma unroll
        for (int reg = 0; reg < 4; ++reg) {
            Hs[(rbase + reg) * 132 + col0] = tanhf(acc0[reg] + b1[col0]);
            Hs[(rbase + reg) * 132 + col0 + 16] = tanhf(acc1[reg] + b1[col0 + 16]);
        }
    }
    __syncthreads();
    {
        const float* Hs = (const float*)smem;
        const int r = t >> 4;
        const int g = t & 15;
        const int u = u0 + r;
        const unsigned sdw2 = SD[u];
        unsigned vocab = 0;
        if (sdw2 & 1023u)
            vocab = Gb[((sdw2 >> 19) << 9) + ((sdw2 >> 10) & 511u)] >> 9;
        const float4* wrow = (const float4*)(enc + (size_t)vocab * (DMID * DOUT));
        float ax = 0.f, ay = 0.f, az = 0.f, aw = 0.f;
#pragma unroll
        for (int jj = 0; jj < 8; ++jj) {
            int j = jj * 16 + g;
            float4 w4 = wrow[j];
            float hv = Hs[r * 132 + j];
            ax += hv * w4.x; ay += hv * w4.y; az += hv * w4.z; aw += hv * w4.w;
        }
#pragma unroll
        for (int off = 1; off < 16; off <<= 1) {
            ax += __shfl_xor(ax, off);
            ay += __shfl_xor(ay, off);
            az += __shfl_xor(az, off);
            aw += __shfl_xor(aw, off);
        }
        if (g == 0) {
            float4 o;
            o.x = 1.f / (1.f + expf(-ax));
            o.y = 1.f / (1.f + expf(-ay));
            o.z = 1.f / (1.f + expf(-az));
            o.w = 1.f / (1.f + expf(-aw));
            *(float4*)(out_enc + (size_t)u * 4) = o;
        }
    }
}

// ===========================================================================
// FALLBACK (proven R6): single-block LDS sort + transpose + RS-based fused.
// ===========================================================================
#define SORT_SMEM (65536 + 65536 + 4096 + 64)

__global__ __launch_bounds__(1024) void sort_transpose_kernel(
    const int* __restrict__ vocab_ids,
    const float* __restrict__ W1,
    unsigned int* __restrict__ G,
    unsigned short* __restrict__ RS,
    unsigned short* __restrict__ WtG,
    float* __restrict__ out_ids) {
    const int t = threadIdx.x;
    if (blockIdx.x != 0) {
        int idx = (blockIdx.x - 1) * 1024 + t;
        if (idx < DMID * DIN) {
            int c = idx / DIN;
            int k = idx - c * DIN;
            WtG[idx] = (unsigned short)f2bf(W1[k * DMID + c]);
        }
        return;
    }
    extern __shared__ char smem[];
    unsigned* Gs     = (unsigned*)smem;
    unsigned* histDM = (unsigned*)(smem + 65536);
    unsigned* sums   = (unsigned*)(smem + 131072);
    unsigned* totalU = (unsigned*)(smem + 135168);
    for (int e = t; e < NELEM; e += 1024)
        Gs[e] = ((unsigned)vocab_ids[e] << 14) | (unsigned)e;
    __syncthreads();
    for (int pass = 0; pass < 6; ++pass) {
        const int shift = 9 + pass * 4;
        unsigned v[16];
#pragma unroll
        for (int i = 0; i < 16; ++i) v[i] = Gs[t * 16 + i];
#pragma unroll
        for (int d = 0; d < 16; ++d) histDM[d * 1024 + t] = 0;
#pragma unroll
        for (int i = 0; i < 16; ++i) histDM[((v[i] >> shift) & 15u) * 1024 + t] += 1;
        __syncthreads();
        unsigned lex[16]; unsigned run = 0;
#pragma unroll
        for (int i = 0; i < 16; ++i) { unsigned x = histDM[t * 16 + i]; lex[i] = run; run += x; }
        sums[t] = run;
        __syncthreads();
        if (t < 64) {
            unsigned s[16]; unsigned tot = 0;
#pragma unroll
            for (int i = 0; i < 16; ++i) { unsigned x = sums[t * 16 + i]; s[i] = tot; tot += x; }
            unsigned incv = tot;
#pragma unroll
            for (int off = 1; off < 64; off <<= 1) {
                unsigned y = __shfl_up(incv, off);
                if (t >= off) incv += y;
            }
            unsigned excl = incv - tot;
#pragma unroll
            for (int i = 0; i < 16; ++i) sums[t * 16 + i] = excl + s[i];
        }
        __syncthreads();
#pragma unroll
        for (int i = 0; i < 16; ++i) histDM[t * 16 + i] = sums[t] + lex[i];
        __syncthreads();
        unsigned mycnt[16];
#pragma unroll
        for (int d = 0; d < 16; ++d) mycnt[d] = histDM[d * 1024 + t];
#pragma unroll
        for (int i = 0; i < 16; ++i) {
            unsigned d = (v[i] >> shift) & 15u;
            Gs[mycnt[d]++] = v[i];
        }
        __syncthreads();
    }
    unsigned v[16];
#pragma unroll
    for (int i = 0; i < 16; ++i) v[i] = Gs[t * 16 + i];
    unsigned pk = (t == 0) ? 0xFFFFFFFFu : (Gs[t * 16 - 1] >> 9);
    unsigned fm = 0;
#pragma unroll
    for (int i = 0; i < 16; ++i) {
        unsigned key = v[i] >> 9;
        if (key != pk) fm |= (1u << i);
        pk = key;
    }
    sums[t] = (unsigned)__popc(fm);
    __syncthreads();
    if (t < 64) {
        unsigned s[16]; unsigned tot = 0;
#pragma unroll
        for (int i = 0; i < 16; ++i) { unsigned x = sums[t * 16 + i]; s[i] = tot; tot += x; }
        unsigned incv = tot;
#pragma unroll
        for (int off = 1; off < 64; off <<= 1) {
            unsigned y = __shfl_up(incv, off);
            if (t >= off) incv += y;
        }
        unsigned excl = incv - tot;
#pragma unroll
        for (int i = 0; i < 16; ++i) sums[t * 16 + i] = excl + s[i];
        if (t == 63) *totalU = incv;
    }
    __syncthreads();
    unsigned r = sums[t];
#pragma unroll
    for (int i = 0; i < 16; ++i) {
        if (fm & (1u << i)) {
            RS[r] = (unsigned short)(t * 16 + i);
            out_ids[2 * r + 0] = (float)(v[i] >> 14);
            out_ids[2 * r + 1] = (float)((v[i] >> 9) & 31u);
            ++r;
        }
    }
    const unsigned U = *totalU;
    for (int u = t; u < NELEM; u += 1024) {
        if ((unsigned)u >= U) {
            RS[u] = (unsigned short)NELEM;
            out_ids[2 * u + 0] = 0.0f;
            out_ids[2 * u + 1] = 0.0f;
        }
        G[u] = Gs[u];
    }
    if (t == 0) RS[NELEM] = (unsigned short)NELEM;
}

__global__ __launch_bounds__(256) void fused_kernel_rs(
    const unsigned* __restrict__ G,
    const unsigned short* __restrict__ RS,
    const unsigned short* __restrict__ WtG,
    const float* __restrict__ emb,
    const float* __restrict__ b1,
    const float* __restrict__ enc,
    float* __restrict__ out_enc) {
    __shared__ char smem[20736];
    const int t = threadIdx.x;
    const int u0 = blockIdx.x * FBM;
    const int l = t & 63;
    const int w = t >> 6;
    const int ar = t >> 4;
    const int ak4 = t & 15;
    const int rs_a = (int)RS[u0 + ar];
    const int re_a = (int)RS[u0 + ar + 1];
    f32x4 acc0 = {0.f, 0.f, 0.f, 0.f};
    f32x4 acc1 = {0.f, 0.f, 0.f, 0.f};
    for (int kk = 0; kk < DIN; kk += 64) {
        __syncthreads();
        {
            float s0 = 0.f, s1 = 0.f, s2 = 0.f, s3 = 0.f;
            const float* base = emb + (size_t)(kk + ak4 * 4);
            for (int p = rs_a; p < re_a; ++p) {
                unsigned idx = G[p] & 16383u;
                const float4 e4 = *(const float4*)(base + (size_t)idx * DIN);
                s0 += e4.x; s1 += e4.y; s2 += e4.z; s3 += e4.w;
            }
            uint2 packed;
            packed.x = f2bf(s0) | (f2bf(s1) << 16);
            packed.y = f2bf(s2) | (f2bf(s3) << 16);
            *(uint2*)(smem + ar * 144 + ak4 * 8) = packed;
        }
        {
#pragma unroll
            for (int i = 0; i < 4; ++i) {
                int q = t + i * 256;
                int c = q >> 3;
                int uo = q & 7;
                uint4 dv = *(const uint4*)(WtG + (size_t)c * DIN + kk + uo * 8);
                *(uint4*)(smem + 2304 + c * 144 + uo * 16) = dv;
            }
        }
        __syncthreads();
        {
            const int arow = l & 15;
            const int ull = l >> 4;
#pragma unroll
            for (int kf = 0; kf < 2; ++kf) {
                short8 aF = *(const short8*)(smem + arow * 144 + kf * 64 + ull * 16);
                short8 bF0 = *(const short8*)(smem + 2304 + (w * 32 + arow) * 144 + kf * 64 + ull * 16);
                short8 bF1 = *(const short8*)(smem + 2304 + (w * 32 + 16 + arow) * 144 + kf * 64 + ull * 16);
                acc0 = __builtin_amdgcn_mfma_f32_16x16x32_bf16(aF, bF0, acc0, 0, 0, 0);
                acc1 = __builtin_amdgcn_mfma_f32_16x16x32_bf16(aF, bF1, acc1, 0, 0, 0);
            }
        }
    }
    __syncthreads();
    {
        float* Hs = (float*)smem;
        const int col0 = w * 32 + (l & 15);
        const int rbase = (l >> 4) * 4;
#pragma unroll
        for (int reg = 0; reg < 4; ++reg) {
            Hs[(rbase + reg) * 132 + col0] = tanhf(acc0[reg] + b1[col0]);
            Hs[(rbase + reg) * 132 + col0 + 16] = tanhf(acc1[reg] + b1[col0 + 16]);
        }
    }
    __syncthreads();
    {
        const float* Hs = (const float*)smem;
        const int r = t >> 4;
        const int g = t & 15;
        const int u = u0 + r;
        const int rs = (int)RS[u];
        const int re = (int)RS[u + 1];
        unsigned vocab = (rs < re) ? (G[rs] >> 14) : 0u;
        const float4* wrow = (const float4*)(enc + (size_t)vocab * (DMID * DOUT));
        float ax = 0.f, ay = 0.f, az = 0.f, aw = 0.f;
#pragma unroll
        for (int jj = 0; jj < 8; ++jj) {
            int j = jj * 16 + g;
            float4 w4 = wrow[j];
            float hv = Hs[r * 132 + j];
            ax += hv * w4.x; ay += hv * w4.y; az += hv * w4.z; aw += hv * w4.w;
        }
#pragma unroll
        for (int off = 1; off < 16; off <<= 1) {
            ax += __shfl_xor(ax, off);
            ay += __shfl_xor(ay, off);
            az += __shfl_xor(az, off);
            aw += __shfl_xor(aw, off);
        }
        if (g == 0) {
            float4 o;
            o.x = 1.f / (1.f + expf(-ax));
            o.y = 1.f / (1.f + expf(-az));
            o.y = 1.f / (1.f + expf(-ay));
            o.z = 1.f / (1.f + expf(-az));
            o.w = 1.f / (1.f + expf(-aw));
            *(float4*)(out_enc + (size_t)u * 4) = o;
        }
    }
}

// ---------------------------------------------------------------------------
extern "C" void kernel_launch(void* const* d_in, const int* in_sizes, int n_in,
                              void* d_out, int out_size, void* d_ws, size_t ws_size,
                              hipStream_t stream) {
    const int*   vocab_ids = (const int*)d_in[0];
    const float* emb       = (const float*)d_in[1];
    const float* W1        = (const float*)d_in[2];
    const float* b1        = (const float*)d_in[3];
    const float* enc       = (const float*)d_in[4];
    float* out = (float*)d_out;
    float* out_ids = out;
    float* out_enc = out + NELEM * 2;
    char* ws = (char*)d_ws;

    if (ws_size >= FAST5_WS) {
        unsigned*           Gb    = (unsigned*)(ws + 0);
        unsigned*           SD    = (unsigned*)(ws + 65536);
        unsigned short*     WtG   = (unsigned short*)(ws + 131072);
        unsigned long long* stage = (unsigned long long*)(ws + 327680);
        unsigned*           LCnt  = (unsigned*)(ws + 458752);
        unsigned*           RBT   = (unsigned*)(ws + 458880);

        prep_kernel<<<32, 256, 0, stream>>>(vocab_ids, W1, Gb, WtG, RBT, stage, LCnt);
        // MEASUREMENT: rank x3 (idempotent). T = base + 2*rank.
        rank_kernel<<<32, 256, 0, stream>>>(RBT, stage, LCnt, SD, out_ids);
        rank_kernel<<<32, 256, 0, stream>>>(RBT, stage, LCnt, SD, out_ids);
        rank_kernel<<<32, 256, 0, stream>>>(RBT, stage, LCnt, SD, out_ids);
        fused_kernel<<<NELEM / FBM, 256, 0, stream>>>(Gb, SD, WtG, emb, b1, enc, out_enc);
    } else {
        unsigned int*   G   = (unsigned int*)(ws);
        unsigned short* RS  = (unsigned short*)(ws + 65536);
        unsigned short* WtG = (unsigned short*)(ws + 98432);

        hipFuncSetAttribute((const void*)sort_transpose_kernel,
                            hipFuncAttributeMaxDynamicSharedMemorySize, SORT_SMEM);
        sort_transpose_kernel<<<1 + 96, 1024, SORT_SMEM, stream>>>(
            vocab_ids, W1, G, RS, WtG, out_ids);
        fused_kernel_rs<<<NELEM / FBM, 256, 0, stream>>>(G, RS, WtG, emb, b1, enc, out_enc);
    }
}

// Round 16
// 60.076 us; speedup vs baseline: 1.8168x; 1.8168x over previous
//
#include <hip/hip_runtime.h>
#include <hip/hip_bf16.h>

#define NELEM 16384
#define DIN 768
#define DMID 128
#define DOUT 4

typedef __attribute__((ext_vector_type(8))) short short8;
typedef __attribute__((ext_vector_type(4))) float f32x4;

__device__ __forceinline__ unsigned f2bf(float f) {
    unsigned u = __float_as_uint(f);
    return (u + 0x7FFFu + ((u >> 16) & 1u)) >> 16;   // RNE bf16
}
__device__ __forceinline__ unsigned wscan_inc(unsigned x, int lane) {
    unsigned inc = x;
#pragma unroll
    for (int off = 1; off < 64; off <<= 1) {
        unsigned y = __shfl_up(inc, off);
        if (lane >= off) inc += y;
    }
    return inc;
}

// ===========================================================================
// FAST6 ws layout:
//   Gb@0(64K) SD@65536(64K) WtG@131072(192K) stage@327680(128K u64)
//   LCnt@458752(128) RB@458880(512K row-LINEAR row-bitmaps)  -> 983,168 B
// Gb word = vocab<<9 | s ; SD[u] = b<<19 | start<<10 | len
// stage[b*512+g] = (u64)vocab<<32 | SDvalue ; LCnt[b] = #groups in row b
// RB[b*4096 + w] = word w of row b's vocab bitmap; fully overwritten by prep.
// ===========================================================================
#define FAST6_WS 983168

// K1: 128 blocks. Blocks 0..31: per-row grouping (coalesced RB dump).
//     Blocks 32..127: W1^T -> bf16 with coalesced writes.
__global__ __launch_bounds__(256) void prep_kernel(
    const int* __restrict__ vocab_ids, const float* __restrict__ W1,
    unsigned* __restrict__ Gb, unsigned short* __restrict__ WtG,
    unsigned* __restrict__ RB, unsigned long long* __restrict__ stage,
    unsigned* __restrict__ LCnt) {
    const int t = threadIdx.x;
    const int blk = blockIdx.x;

    if (blk >= 32) {
        // ---- W1^T: 96 blocks x 1024 outputs. Thread -> 4 consecutive k's of
        // one column c; coalesced uint2 writes, strided cached reads. ----
        int o = (blk - 32) * 1024 + t * 4;          // 0..98300, mult of 4
        int c = o / DIN;
        int k = o - c * DIN;                        // mult of 4, k+3 < DIN
        unsigned p0 = f2bf(W1[(k + 0) * DMID + c]) | (f2bf(W1[(k + 1) * DMID + c]) << 16);
        unsigned p1 = f2bf(W1[(k + 2) * DMID + c]) | (f2bf(W1[(k + 3) * DMID + c]) << 16);
        uint2 pk2; pk2.x = p0; pk2.y = p1;
        *(uint2*)(WtG + (size_t)c * DIN + k) = pk2;
        return;
    }

    __shared__ unsigned lbm[4096];       // 16 KB row vocab bitmap (2^17 bits)
    __shared__ unsigned voc[512];
    __shared__ unsigned short gel[512];
    __shared__ unsigned gcnt[512];
    __shared__ unsigned gstart[512];
    __shared__ unsigned part[256];
    __shared__ unsigned wsumL[4];

    const int b = blk;
    const int lane = t & 63;
    const int wv = t >> 6;

    // ---- load row + zero LDS ----
#pragma unroll
    for (int i = 0; i < 16; ++i) lbm[t + 256 * i] = 0;
    gcnt[t] = 0; gcnt[t + 256] = 0;
#pragma unroll
    for (int q = 0; q < 2; ++q) {
        int s = q * 256 + t;
        voc[s] = (unsigned)vocab_ids[b * 512 + s];
    }
    __syncthreads();
    // ---- local bitmap mark (LDS atomics only) ----
#pragma unroll
    for (int q = 0; q < 2; ++q) {
        unsigned v = voc[q * 256 + t];
        atomicOr(&lbm[v >> 5], 1u << (v & 31u));
    }
    __syncthreads();
    // ---- dump row bitmap to global, LINEAR + COALESCED ----
#pragma unroll
    for (int i = 0; i < 4; ++i) {
        int w4 = i * 256 + t;                       // uint4 index 0..1023
        uint4 x;
        x.x = lbm[w4 * 4 + 0]; x.y = lbm[w4 * 4 + 1];
        x.z = lbm[w4 * 4 + 2]; x.w = lbm[w4 * 4 + 3];
        *(uint4*)(RB + (size_t)b * 4096 + w4 * 4) = x;
    }
    // ---- local chunk-scan (16 words/thread) -> part[]; LCnt = #groups ----
    {
        unsigned sum = 0;
#pragma unroll
        for (int j = 0; j < 16; ++j) sum += (unsigned)__popc(lbm[t * 16 + j]);
        unsigned inc = wscan_inc(sum, lane);
        if (lane == 63) wsumL[wv] = inc;
        __syncthreads();
        unsigned woff = 0;
        for (int i = 0; i < wv; ++i) woff += wsumL[i];
        part[t] = woff + inc - sum;
        if (t == 255) LCnt[b] = woff + inc;
        __syncthreads();
    }
    // ---- per-element group index g; count group sizes ----
#pragma unroll
    for (int q = 0; q < 2; ++q) {
        int s = q * 256 + t;
        unsigned v = voc[s];
        unsigned lw = v >> 5, c = lw >> 4;
        unsigned g = part[c];
        for (unsigned j = c * 16; j < lw; ++j) g += (unsigned)__popc(lbm[j]);
        g += (unsigned)__popc(lbm[lw] & ((1u << (v & 31u)) - 1u));
        gel[s] = (unsigned short)g;
        atomicAdd(&gcnt[g], 1u);                    // LDS, counts only
    }
    __syncthreads();
    // ---- exclusive scan gcnt[512] -> gstart ----
    {
        unsigned a = gcnt[2 * t], b2 = gcnt[2 * t + 1];
        unsigned pair = a + b2;
        unsigned inc = wscan_inc(pair, lane);
        if (lane == 63) wsumL[wv] = inc;
        __syncthreads();
        unsigned woff = 0;
        for (int i = 0; i < wv; ++i) woff += wsumL[i];
        unsigned excl = woff + inc - pair;
        gstart[2 * t] = excl;
        gstart[2 * t + 1] = excl + a;
    }
    __syncthreads();
    // ---- member index + grouped Gb write + leader staging ----
#pragma unroll
    for (int q = 0; q < 2; ++q) {
        int s = q * 256 + t;
        unsigned g = gel[s];
        unsigned v = voc[s];
        unsigned m = 0;
        if (gcnt[g] > 1) {                          // rare
            for (int j = 0; j < s; ++j) if (voc[j] == v) ++m;
        }
        Gb[b * 512 + gstart[g] + m] = (v << 9) | (unsigned)s;
        if (m == 0) {
            unsigned sdval = ((unsigned)b << 19) | (gstart[g] << 10) | gcnt[g];
            stage[b * 512 + g] = ((unsigned long long)v << 32) | sdval;
        }
    }
}

// K2: rank. 32 blocks x 256 threads. Coalesced 32-row stream -> pre1 LDS;
// leader rank = pre1[w] + 32-row column popc (+tie-break), cached loads.
__global__ __launch_bounds__(256) void rank_kernel(
    const unsigned* __restrict__ RB,
    const unsigned long long* __restrict__ stage,
    const unsigned* __restrict__ LCnt,
    unsigned* __restrict__ SD, float* __restrict__ out_ids) {
    __shared__ unsigned pre1[4096];      // 16 KB: cross-row bit-prefix per word
    __shared__ unsigned wsumL[4];
    __shared__ unsigned Ush;

    const int t = threadIdx.x;
    const int b = blockIdx.x;
    const int lane = t & 63;
    const int wv = t >> 6;
    const uint4* rb4 = (const uint4*)RB;

    // ---- colsum scan: thread owns words [t*16, t*16+16) = uint4 [t*4, t*4+4)
    {
        unsigned cs[16];
#pragma unroll
        for (int i = 0; i < 16; ++i) cs[i] = 0;
#pragma unroll 4
        for (int b2 = 0; b2 < 32; ++b2) {
            const uint4* rp = rb4 + b2 * 1024 + t * 4;
#pragma unroll
            for (int q = 0; q < 4; ++q) {
                uint4 x = rp[q];
                cs[q * 4 + 0] += (unsigned)__popc(x.x);
                cs[q * 4 + 1] += (unsigned)__popc(x.y);
                cs[q * 4 + 2] += (unsigned)__popc(x.z);
                cs[q * 4 + 3] += (unsigned)__popc(x.w);
            }
        }
        unsigned loc[16];
        unsigned run = 0;
#pragma unroll
        for (int i = 0; i < 16; ++i) { loc[i] = run; run += cs[i]; }
        unsigned inc = wscan_inc(run, lane);
        if (lane == 63) wsumL[wv] = inc;
        __syncthreads();
        unsigned woff = 0;
        for (int i = 0; i < wv; ++i) woff += wsumL[i];
        unsigned excl = woff + inc - run;
#pragma unroll
        for (int i = 0; i < 16; ++i) pre1[t * 16 + i] = excl + loc[i];
        if (t == 255) Ush = woff + inc;
        __syncthreads();
    }
    const unsigned U = Ush;

    // ---- leaders of row b: rank + SD + ids ----
    const unsigned cnt = LCnt[b];
    for (unsigned l = t; l < cnt; l += 256) {
        unsigned long long sv = stage[b * 512 + l];
        unsigned v = (unsigned)(sv >> 32);
        unsigned sdval = (unsigned)sv;
        unsigned w = v >> 5, bit = v & 31u;
        unsigned maskLT = (1u << bit) - 1u;
        unsigned rank = pre1[w];
#pragma unroll 8
        for (int b2 = 0; b2 < 32; ++b2) {
            unsigned word = RB[b2 * 4096 + w];
            rank += (unsigned)__popc(word & maskLT);
            if (b2 < b) rank += (word >> bit) & 1u;
        }
        SD[rank] = sdval;
        out_ids[2 * rank + 0] = (float)v;
        out_ids[2 * rank + 1] = (float)b;
    }
    // ---- pad slots >= U ----
    for (int u = (int)U + b * 256 + t; u < NELEM; u += 32 * 256) {
        SD[u] = 0u;
        out_ids[2 * u + 0] = 0.0f;
        out_ids[2 * u + 1] = 0.0f;
    }
}

// ===========================================================================
// K3: MFMA fused kernel (proven R10-R15). 1024 blocks x 256 thr, 16 rows.
// ===========================================================================
#define FBM 16
__global__ __launch_bounds__(256) void fused_kernel(
    const unsigned* __restrict__ Gb,
    const unsigned* __restrict__ SD,
    const unsigned short* __restrict__ WtG,
    const float* __restrict__ emb,
    const float* __restrict__ b1,
    const float* __restrict__ enc,
    float* __restrict__ out_enc) {
    __shared__ char smem[20736];

    const int t = threadIdx.x;
    const int u0 = blockIdx.x * FBM;
    const int l = t & 63;
    const int w = t >> 6;

    const int ar = t >> 4;
    const int ak4 = t & 15;
    const unsigned sdw = SD[u0 + ar];
    const int lenA = (int)(sdw & 1023u);
    const unsigned embBase = (sdw >> 19) << 9;
    const unsigned gb0 = embBase + ((sdw >> 10) & 511u);

    f32x4 acc0 = {0.f, 0.f, 0.f, 0.f};
    f32x4 acc1 = {0.f, 0.f, 0.f, 0.f};

    for (int kk = 0; kk < DIN; kk += 64) {
        __syncthreads();
        {
            float s0 = 0.f, s1 = 0.f, s2 = 0.f, s3 = 0.f;
            const float* base = emb + (size_t)(kk + ak4 * 4);
            for (int p = 0; p < lenA; ++p) {
                unsigned idx = embBase + (Gb[gb0 + p] & 511u);
                const float4 e4 = *(const float4*)(base + (size_t)idx * DIN);
                s0 += e4.x; s1 += e4.y; s2 += e4.z; s3 += e4.w;
            }
            uint2 packed;
            packed.x = f2bf(s0) | (f2bf(s1) << 16);
            packed.y = f2bf(s2) | (f2bf(s3) << 16);
            *(uint2*)(smem + ar * 144 + ak4 * 8) = packed;
        }
        {
#pragma unroll
            for (int i = 0; i < 4; ++i) {
                int q = t + i * 256;
                int c = q >> 3;
                int uo = q & 7;
                uint4 dv = *(const uint4*)(WtG + (size_t)c * DIN + kk + uo * 8);
                *(uint4*)(smem + 2304 + c * 144 + uo * 16) = dv;
            }
        }
        __syncthreads();
        {
            const int arow = l & 15;
            const int ull = l >> 4;
#pragma unroll
            for (int kf = 0; kf < 2; ++kf) {
                short8 aF = *(const short8*)(smem + arow * 144 + kf * 64 + ull * 16);
                short8 bF0 = *(const short8*)(smem + 2304 + (w * 32 + arow) * 144 + kf * 64 + ull * 16);
                short8 bF1 = *(const short8*)(smem + 2304 + (w * 32 + 16 + arow) * 144 + kf * 64 + ull * 16);
                acc0 = __builtin_amdgcn_mfma_f32_16x16x32_bf16(aF, bF0, acc0, 0, 0, 0);
                acc1 = __builtin_amdgcn_mfma_f32_16x16x32_bf16(aF, bF1, acc1, 0, 0, 0);
            }
        }
    }
    __syncthreads();
    {
        float* Hs = (float*)smem;
        const int col0 = w * 32 + (l & 15);
        const int rbase = (l >> 4) * 4;
#pragma unroll
        for (int reg = 0; reg < 4; ++reg) {
            Hs[(rbase + reg) * 132 + col0] = tanhf(acc0[reg] + b1[col0]);
            Hs[(rbase + reg) * 132 + col0 + 16] = tanhf(acc1[reg] + b1[col0 + 16]);
        }
    }
    __syncthreads();
    {
        const float* Hs = (const float*)smem;
        const int r = t >> 4;
        const int g = t & 15;
        const int u = u0 + r;
        const unsigned sdw2 = SD[u];
        unsigned vocab = 0;
        if (sdw2 & 1023u)
            vocab = Gb[((sdw2 >> 19) << 9) + ((sdw2 >> 10) & 511u)] >> 9;
        const float4* wrow = (const float4*)(enc + (size_t)vocab * (DMID * DOUT));
        float ax = 0.f, ay = 0.f, az = 0.f, aw = 0.f;
#pragma unroll
        for (int jj = 0; jj < 8; ++jj) {
            int j = jj * 16 + g;
            float4 w4 = wrow[j];
            float hv = Hs[r * 132 + j];
            ax += hv * w4.x; ay += hv * w4.y; az += hv * w4.z; aw += hv * w4.w;
        }
#pragma unroll
        for (int off = 1; off < 16; off <<= 1) {
            ax += __shfl_xor(ax, off);
            ay += __shfl_xor(ay, off);
            az += __shfl_xor(az, off);
            aw += __shfl_xor(aw, off);
        }
        if (g == 0) {
            float4 o;
            o.x = 1.f / (1.f + expf(-ax));
            o.y = 1.f / (1.f + expf(-ay));
            o.z = 1.f / (1.f + expf(-az));
            o.w = 1.f / (1.f + expf(-aw));
            *(float4*)(out_enc + (size_t)u * 4) = o;
        }
    }
}

// ===========================================================================
// FALLBACK (proven R6): single-block LDS sort + transpose + RS-based fused.
// ===========================================================================
#define SORT_SMEM (65536 + 65536 + 4096 + 64)

__global__ __launch_bounds__(1024) void sort_transpose_kernel(
    const int* __restrict__ vocab_ids,
    const float* __restrict__ W1,
    unsigned int* __restrict__ G,
    unsigned short* __restrict__ RS,
    unsigned short* __restrict__ WtG,
    float* __restrict__ out_ids) {
    const int t = threadIdx.x;
    if (blockIdx.x != 0) {
        int idx = (blockIdx.x - 1) * 1024 + t;
        if (idx < DMID * DIN) {
            int c = idx / DIN;
            int k = idx - c * DIN;
            WtG[idx] = (unsigned short)f2bf(W1[k * DMID + c]);
        }
        return;
    }
    extern __shared__ char smem[];
    unsigned* Gs     = (unsigned*)smem;
    unsigned* histDM = (unsigned*)(smem + 65536);
    unsigned* sums   = (unsigned*)(smem + 131072);
    unsigned* totalU = (unsigned*)(smem + 135168);
    for (int e = t; e < NELEM; e += 1024)
        Gs[e] = ((unsigned)vocab_ids[e] << 14) | (unsigned)e;
    __syncthreads();
    for (int pass = 0; pass < 6; ++pass) {
        const int shift = 9 + pass * 4;
        unsigned v[16];
#pragma unroll
        for (int i = 0; i < 16; ++i) v[i] = Gs[t * 16 + i];
#pragma unroll
        for (int d = 0; d < 16; ++d) histDM[d * 1024 + t] = 0;
#pragma unroll
        for (int i = 0; i < 16; ++i) histDM[((v[i] >> shift) & 15u) * 1024 + t] += 1;
        __syncthreads();
        unsigned lex[16]; unsigned run = 0;
#pragma unroll
        for (int i = 0; i < 16; ++i) { unsigned x = histDM[t * 16 + i]; lex[i] = run; run += x; }
        sums[t] = run;
        __syncthreads();
        if (t < 64) {
            unsigned s[16]; unsigned tot = 0;
#pragma unroll
            for (int i = 0; i < 16; ++i) { unsigned x = sums[t * 16 + i]; s[i] = tot; tot += x; }
            unsigned incv = tot;
#pragma unroll
            for (int off = 1; off < 64; off <<= 1) {
                unsigned y = __shfl_up(incv, off);
                if (t >= off) incv += y;
            }
            unsigned excl = incv - tot;
#pragma unroll
            for (int i = 0; i < 16; ++i) sums[t * 16 + i] = excl + s[i];
        }
        __syncthreads();
#pragma unroll
        for (int i = 0; i < 16; ++i) histDM[t * 16 + i] = sums[t] + lex[i];
        __syncthreads();
        unsigned mycnt[16];
#pragma unroll
        for (int d = 0; d < 16; ++d) mycnt[d] = histDM[d * 1024 + t];
#pragma unroll
        for (int i = 0; i < 16; ++i) {
            unsigned d = (v[i] >> shift) & 15u;
            Gs[mycnt[d]++] = v[i];
        }
        __syncthreads();
    }
    unsigned v[16];
#pragma unroll
    for (int i = 0; i < 16; ++i) v[i] = Gs[t * 16 + i];
    unsigned pk = (t == 0) ? 0xFFFFFFFFu : (Gs[t * 16 - 1] >> 9);
    unsigned fm = 0;
#pragma unroll
    for (int i = 0; i < 16; ++i) {
        unsigned key = v[i] >> 9;
        if (key != pk) fm |= (1u << i);
        pk = key;
    }
    sums[t] = (unsigned)__popc(fm);
    __syncthreads();
    if (t < 64) {
        unsigned s[16]; unsigned tot = 0;
#pragma unroll
        for (int i = 0; i < 16; ++i) { unsigned x = sums[t * 16 + i]; s[i] = tot; tot += x; }
        unsigned incv = tot;
#pragma unroll
        for (int off = 1; off < 64; off <<= 1) {
            unsigned y = __shfl_up(incv, off);
            if (t >= off) incv += y;
        }
        unsigned excl = incv - tot;
#pragma unroll
        for (int i = 0; i < 16; ++i) sums[t * 16 + i] = excl + s[i];
        if (t == 63) *totalU = incv;
    }
    __syncthreads();
    unsigned r = sums[t];
#pragma unroll
    for (int i = 0; i < 16; ++i) {
        if (fm & (1u << i)) {
            RS[r] = (unsigned short)(t * 16 + i);
            out_ids[2 * r + 0] = (float)(v[i] >> 14);
            out_ids[2 * r + 1] = (float)((v[i] >> 9) & 31u);
            ++r;
        }
    }
    const unsigned U = *totalU;
    for (int u = t; u < NELEM; u += 1024) {
        if ((unsigned)u >= U) {
            RS[u] = (unsigned short)NELEM;
            out_ids[2 * u + 0] = 0.0f;
            out_ids[2 * u + 1] = 0.0f;
        }
        G[u] = Gs[u];
    }
    if (t == 0) RS[NELEM] = (unsigned short)NELEM;
}

__global__ __launch_bounds__(256) void fused_kernel_rs(
    const unsigned* __restrict__ G,
    const unsigned short* __restrict__ RS,
    const unsigned short* __restrict__ WtG,
    const float* __restrict__ emb,
    const float* __restrict__ b1,
    const float* __restrict__ enc,
    float* __restrict__ out_enc) {
    __shared__ char smem[20736];
    const int t = threadIdx.x;
    const int u0 = blockIdx.x * FBM;
    const int l = t & 63;
    const int w = t >> 6;
    const int ar = t >> 4;
    const int ak4 = t & 15;
    const int rs_a = (int)RS[u0 + ar];
    const int re_a = (int)RS[u0 + ar + 1];
    f32x4 acc0 = {0.f, 0.f, 0.f, 0.f};
    f32x4 acc1 = {0.f, 0.f, 0.f, 0.f};
    for (int kk = 0; kk < DIN; kk += 64) {
        __syncthreads();
        {
            float s0 = 0.f, s1 = 0.f, s2 = 0.f, s3 = 0.f;
            const float* base = emb + (size_t)(kk + ak4 * 4);
            for (int p = rs_a; p < re_a; ++p) {
                unsigned idx = G[p] & 16383u;
                const float4 e4 = *(const float4*)(base + (size_t)idx * DIN);
                s0 += e4.x; s1 += e4.y; s2 += e4.z; s3 += e4.w;
            }
            uint2 packed;
            packed.x = f2bf(s0) | (f2bf(s1) << 16);
            packed.y = f2bf(s2) | (f2bf(s3) << 16);
            *(uint2*)(smem + ar * 144 + ak4 * 8) = packed;
        }
        {
#pragma unroll
            for (int i = 0; i < 4; ++i) {
                int q = t + i * 256;
                int c = q >> 3;
                int uo = q & 7;
                uint4 dv = *(const uint4*)(WtG + (size_t)c * DIN + kk + uo * 8);
                *(uint4*)(smem + 2304 + c * 144 + uo * 16) = dv;
            }
        }
        __syncthreads();
        {
            const int arow = l & 15;
            const int ull = l >> 4;
#pragma unroll
            for (int kf = 0; kf < 2; ++kf) {
                short8 aF = *(const short8*)(smem + arow * 144 + kf * 64 + ull * 16);
                short8 bF0 = *(const short8*)(smem + 2304 + (w * 32 + arow) * 144 + kf * 64 + ull * 16);
                short8 bF1 = *(const short8*)(smem + 2304 + (w * 32 + 16 + arow) * 144 + kf * 64 + ull * 16);
                acc0 = __builtin_amdgcn_mfma_f32_16x16x32_bf16(aF, bF0, acc0, 0, 0, 0);
                acc1 = __builtin_amdgcn_mfma_f32_16x16x32_bf16(aF, bF1, acc1, 0, 0, 0);
            }
        }
    }
    __syncthreads();
    {
        float* Hs = (float*)smem;
        const int col0 = w * 32 + (l & 15);
        const int rbase = (l >> 4) * 4;
#pragma unroll
        for (int reg = 0; reg < 4; ++reg) {
            Hs[(rbase + reg) * 132 + col0] = tanhf(acc0[reg] + b1[col0]);
            Hs[(rbase + reg) * 132 + col0 + 16] = tanhf(acc1[reg] + b1[col0 + 16]);
        }
    }
    __syncthreads();
    {
        const float* Hs = (const float*)smem;
        const int r = t >> 4;
        const int g = t & 15;
        const int u = u0 + r;
        const int rs = (int)RS[u];
        const int re = (int)RS[u + 1];
        unsigned vocab = (rs < re) ? (G[rs] >> 14) : 0u;
        const float4* wrow = (const float4*)(enc + (size_t)vocab * (DMID * DOUT));
        float ax = 0.f, ay = 0.f, az = 0.f, aw = 0.f;
#pragma unroll
        for (int jj = 0; jj < 8; ++jj) {
            int j = jj * 16 + g;
            float4 w4 = wrow[j];
            float hv = Hs[r * 132 + j];
            ax += hv * w4.x; ay += hv * w4.y; az += hv * w4.z; aw += hv * w4.w;
        }
#pragma unroll
        for (int off = 1; off < 16; off <<= 1) {
            ax += __shfl_xor(ax, off);
            ay += __shfl_xor(ay, off);
            az += __shfl_xor(az, off);
            aw += __shfl_xor(aw, off);
        }
        if (g == 0) {
            float4 o;
            o.x = 1.f / (1.f + expf(-ax));
            o.y = 1.f / (1.f + expf(-ay));
            o.z = 1.f / (1.f + expf(-az));
            o.w = 1.f / (1.f + expf(-aw));
            *(float4*)(out_enc + (size_t)u * 4) = o;
        }
    }
}

// ---------------------------------------------------------------------------
extern "C" void kernel_launch(void* const* d_in, const int* in_sizes, int n_in,
                              void* d_out, int out_size, void* d_ws, size_t ws_size,
                              hipStream_t stream) {
    const int*   vocab_ids = (const int*)d_in[0];
    const float* emb       = (const float*)d_in[1];
    const float* W1        = (const float*)d_in[2];
    const float* b1        = (const float*)d_in[3];
    const float* enc       = (const float*)d_in[4];
    float* out = (float*)d_out;
    float* out_ids = out;
    float* out_enc = out + NELEM * 2;
    char* ws = (char*)d_ws;

    if (ws_size >= FAST6_WS) {
        unsigned*           Gb    = (unsigned*)(ws + 0);
        unsigned*           SD    = (unsigned*)(ws + 65536);
        unsigned short*     WtG   = (unsigned short*)(ws + 131072);
        unsigned long long* stage = (unsigned long long*)(ws + 327680);
        unsigned*           LCnt  = (unsigned*)(ws + 458752);
        unsigned*           RB    = (unsigned*)(ws + 458880);

        prep_kernel<<<128, 256, 0, stream>>>(vocab_ids, W1, Gb, WtG, RB, stage, LCnt);
        rank_kernel<<<32, 256, 0, stream>>>(RB, stage, LCnt, SD, out_ids);
        fused_kernel<<<NELEM / FBM, 256, 0, stream>>>(Gb, SD, WtG, emb, b1, enc, out_enc);
    } else {
        unsigned int*   G   = (unsigned int*)(ws);
        unsigned short* RS  = (unsigned short*)(ws + 65536);
        unsigned short* WtG = (unsigned short*)(ws + 98432);

        hipFuncSetAttribute((const void*)sort_transpose_kernel,
                            hipFuncAttributeMaxDynamicSharedMemorySize, SORT_SMEM);
        sort_transpose_kernel<<<1 + 96, 1024, SORT_SMEM, stream>>>(
            vocab_ids, W1, G, RS, WtG, out_ids);
        fused_kernel_rs<<<NELEM / FBM, 256, 0, stream>>>(G, RS, WtG, emb, b1, enc, out_enc);
    }
}